// Round 4
// baseline (235.415 us; speedup 1.0000x reference)
//
#include <hip/hip_runtime.h>

// Problem constants (match reference)
constexpr int kB = 32;
constexpr int kC = 128;
constexpr int kT = 8192;
constexpr int kK = 33;                       // NUM_CPNTS
constexpr float kDT = 2.0f / (kK - 1);       // 0.0625
constexpr float kInvDT = (kK - 1) / 2.0f;    // 16.0

// Native clang vector type — required by __builtin_nontemporal_* (HIP's
// float4 is a class and is rejected).
typedef float floatx4 __attribute__((ext_vector_type(4)));

// Intercept-form fused table, indexed by u = clamp(floor((x+1)*16)+1, 0, 34):
//   tab[u] = (s_u, q_u) with y = x*s_u + q_u
//   s_u = slopes[min(u,33)]
//   i2  = clamp(u-1, 0, 32); cp = -1 + i2*dt; q_u = cumbias[i2] - cp*s_u
constexpr int kTab = kK + 2;  // 35

__device__ __forceinline__ float pwl_eval(float xv, const float2* __restrict__ tab) {
    float t = fmaf(xv, kInvDT, kInvDT);      // (x+1)*16, single rounding
    int fi = (int)floorf(t);
    int u = min(max(fi + 1, 0), kTab - 1);   // v_med3_i32
    float2 p = tab[u];                       // one ds_read_b64
    return fmaf(xv, p.x, p.y);
}

__global__ __launch_bounds__(256) void pwl_kernel(const float* __restrict__ x,
                                                  const float* __restrict__ slopes,
                                                  const float* __restrict__ biases,
                                                  float* __restrict__ out) {
    __shared__ float sl[kK + 1];   // 34 raw slopes for this channel
    __shared__ float2 tab[kTab];   // 35 fused (slope, intercept) entries

    const int bc = blockIdx.x;          // row index in [0, B*C)
    const int c = bc & (kC - 1);        // channel (C=128 pow2)
    const int tid = threadIdx.x;

    if (tid < kK + 1) sl[tid] = slopes[c * (kK + 1) + tid];
    __syncthreads();
    if (tid < kTab) {
        int su = min(tid, kK);                 // slope index
        int i2 = min(max(tid - 1, 0), kK - 1); // clamped left-breakpoint index
        // cumbias[i2] = bias + dt * sum_{i=1..i2} slopes[i]
        float acc = biases[c];
        for (int i = 1; i <= i2; ++i) acc = fmaf(sl[i], kDT, acc);
        float s = sl[su];
        float cp = fmaf((float)i2, kDT, -1.0f);
        tab[tid] = make_float2(s, fmaf(-cp, s, acc));  // (s, q = cb - cp*s)
    }
    __syncthreads();

    const floatx4* __restrict__ xin =
        reinterpret_cast<const floatx4*>(x) + (size_t)bc * (kT / 4);
    floatx4* __restrict__ o = reinterpret_cast<floatx4*>(out) + (size_t)bc * (kT / 4);

    constexpr int kIters = (kT / 4) / 256;  // 8 float4 per thread

    // 2-deep software pipeline: next load always in flight during compute.
    floatx4 cur = xin[tid];
    #pragma unroll
    for (int k = 0; k < kIters; ++k) {
        floatx4 nxt;
        if (k + 1 < kIters) nxt = xin[tid + (k + 1) * 256];
        floatx4 r;
        r.x = pwl_eval(cur.x, tab);
        r.y = pwl_eval(cur.y, tab);
        r.z = pwl_eval(cur.z, tab);
        r.w = pwl_eval(cur.w, tab);
        // Non-temporal: out is never re-read; keep it from evicting x in LLC.
        __builtin_nontemporal_store(r, &o[tid + k * 256]);
        cur = nxt;
    }
}

extern "C" void kernel_launch(void* const* d_in, const int* in_sizes, int n_in,
                              void* d_out, int out_size, void* d_ws, size_t ws_size,
                              hipStream_t stream) {
    const float* x = (const float*)d_in[0];        // [B, C, T]
    const float* slopes = (const float*)d_in[1];   // [C, K+1]
    const float* biases = (const float*)d_in[2];   // [C]
    float* out = (float*)d_out;                    // [B, C, T]

    // One block per (b, c) row: 4096 blocks x 256 threads.
    pwl_kernel<<<dim3(kB * kC), dim3(256), 0, stream>>>(x, slopes, biases, out);
}

// Round 5
// 234.819 us; speedup vs baseline: 1.0025x; 1.0025x over previous
//
#include <hip/hip_runtime.h>

// Problem constants (match reference)
constexpr int kB = 32;
constexpr int kC = 128;
constexpr int kT = 8192;
constexpr int kK = 33;                       // NUM_CPNTS
constexpr float kDT = 2.0f / (kK - 1);       // 0.0625
constexpr float kInvDT = (kK - 1) / 2.0f;    // 16.0

// Native clang vector type — required by __builtin_nontemporal_* builtins.
typedef float floatx4 __attribute__((ext_vector_type(4)));

// Intercept-form fused table, indexed by u = clamp(floor((x+1)*16)+1, 0, 34):
//   tab[u] = (s_u, q_u) with y = x*s_u + q_u
constexpr int kTab = kK + 2;  // 35

__device__ __forceinline__ float pwl_eval(float xv, const float2* __restrict__ tab) {
    float t = fmaf(xv, kInvDT, kInvDT);      // (x+1)*16, single rounding
    int fi = (int)floorf(t);
    int u = min(max(fi + 1, 0), kTab - 1);   // v_med3_i32
    float2 p = tab[u];                       // one ds_read_b64
    return fmaf(xv, p.x, p.y);
}

__global__ __launch_bounds__(256) void pwl_kernel(const float* __restrict__ x,
                                                  const float* __restrict__ slopes,
                                                  const float* __restrict__ biases,
                                                  float* __restrict__ out) {
    __shared__ float sl[kK + 1];   // 34 raw slopes for this channel
    __shared__ float2 tab[kTab];   // 35 fused (slope, intercept) entries

    const int bc = blockIdx.x;          // row index in [0, B*C)
    const int c = bc & (kC - 1);        // channel (C=128 pow2)
    const int tid = threadIdx.x;

    if (tid < kK + 1) sl[tid] = slopes[c * (kK + 1) + tid];
    __syncthreads();
    if (tid < kTab) {
        int su = min(tid, kK);                 // slope index
        int i2 = min(max(tid - 1, 0), kK - 1); // clamped left-breakpoint index
        float acc = biases[c];                 // cumbias[i2]
        for (int i = 1; i <= i2; ++i) acc = fmaf(sl[i], kDT, acc);
        float s = sl[su];
        float cp = fmaf((float)i2, kDT, -1.0f);
        tab[tid] = make_float2(s, fmaf(-cp, s, acc));  // (s, q = cb - cp*s)
    }
    __syncthreads();

    const floatx4* __restrict__ xin =
        reinterpret_cast<const floatx4*>(x) + (size_t)bc * (kT / 4);
    floatx4* __restrict__ o = reinterpret_cast<floatx4*>(out) + (size_t)bc * (kT / 4);

    constexpr int kIters = (kT / 4) / 256;  // 8 float4 per thread

    // Phase 1: issue ALL 8 global loads — 8 vmcnt ops in flight per wave.
    floatx4 v[kIters];
    #pragma unroll
    for (int k = 0; k < kIters; ++k) v[k] = xin[tid + k * 256];

    // Hard scheduling fence: nothing may cross. Prevents the register
    // allocator from collapsing the load batch back into a rolled
    // load->wait->consume loop (R2/R4 showed it does exactly that: VGPR=24).
    __builtin_amdgcn_sched_barrier(0);

    // Phase 2: consume + store.
    #pragma unroll
    for (int k = 0; k < kIters; ++k) {
        floatx4 r;
        r.x = pwl_eval(v[k].x, tab);
        r.y = pwl_eval(v[k].y, tab);
        r.z = pwl_eval(v[k].z, tab);
        r.w = pwl_eval(v[k].w, tab);
        __builtin_nontemporal_store(r, &o[tid + k * 256]);
    }
}

extern "C" void kernel_launch(void* const* d_in, const int* in_sizes, int n_in,
                              void* d_out, int out_size, void* d_ws, size_t ws_size,
                              hipStream_t stream) {
    const float* x = (const float*)d_in[0];        // [B, C, T]
    const float* slopes = (const float*)d_in[1];   // [C, K+1]
    const float* biases = (const float*)d_in[2];   // [C]
    float* out = (float*)d_out;                    // [B, C, T]

    // One block per (b, c) row: 4096 blocks x 256 threads.
    pwl_kernel<<<dim3(kB * kC), dim3(256), 0, stream>>>(x, slopes, biases, out);
}